// Round 14
// baseline (721.237 us; speedup 1.0000x reference)
//
#include <hip/hip_runtime.h>
#include <hip/hip_bf16.h>
#include <math.h>

// ProtoViT forward: bf16-MFMA GEMMs + MFMA attention; LN fused into consumer
// GEMMs via deterministic per-slice partial stats (no atomics); dist double-
// buffered + XCD-swizzled. 34 dispatches.
// B=16, D=384, DEPTH=6, H=6, HD=64, P=2000, NP=4, N=196, T=197.

#define MROWS 3152   // 16*197

typedef short bf16x8 __attribute__((ext_vector_type(8)));
typedef float f32x4 __attribute__((ext_vector_type(4)));
typedef unsigned short u16;

__device__ __forceinline__ void async_copy16(void* lds, const void* g) {
    __builtin_amdgcn_global_load_lds((const __attribute__((address_space(1))) unsigned int*)g,
                                     (__attribute__((address_space(3))) unsigned int*)lds,
                                     16, 0, 0);
}

__device__ __forceinline__ u16 f2b(float x) {
    __hip_bfloat16 h = __float2bfloat16(x);
    return *(u16*)&h;
}

// ---------------------------------------------------------------- merged prep kernel
__device__ __forceinline__ void wt_tile(const float* __restrict__ W, __hip_bfloat16* __restrict__ Wt,
                                        int K, int N, int id, int ntx, int perlayer,
                                        float (*t)[33], int tid) {
    int z = id / perlayer, rem = id % perlayer;
    int n0 = (rem % ntx) * 32, k0 = (rem / ntx) * 32;
    const float* src = W + (size_t)z * K * N;
    __hip_bfloat16* dst = Wt + (size_t)z * K * N;
    int tx = tid & 31, ty = tid >> 5;
    #pragma unroll
    for (int i = 0; i < 4; ++i) t[ty + i * 8][tx] = src[(size_t)(k0 + ty + i * 8) * N + n0 + tx];
    __syncthreads();
    #pragma unroll
    for (int i = 0; i < 4; ++i)
        dst[(size_t)(n0 + ty + i * 8) * K + k0 + tx] = __float2bfloat16(t[tx][ty + i * 8]);
}

__global__ __launch_bounds__(256) void k_prep(
    const float* __restrict__ patch_w, __hip_bfloat16* __restrict__ wPb,
    const float* __restrict__ cls_tok, const float* __restrict__ pos, float* __restrict__ tok,
    const float* __restrict__ qkv_w, __hip_bfloat16* __restrict__ wQ,
    const float* __restrict__ proj_w, __hip_bfloat16* __restrict__ wPr,
    const float* __restrict__ fc1_w, __hip_bfloat16* __restrict__ wF1,
    const float* __restrict__ fc2_w, __hip_bfloat16* __restrict__ wF2,
    const float* __restrict__ x, __hip_bfloat16* __restrict__ Acol,
    const float* __restrict__ proto, __hip_bfloat16* __restrict__ pn)
{
    __shared__ float t[32][33];
    int bid = blockIdx.x;
    const int tid = threadIdx.x;
    if (bid < 1152) {
        int i = bid * 256 + tid;
        wPb[i] = __float2bfloat16(patch_w[i]);
        if (i < 6144) {
            int b = i / 384, d = i % 384;
            tok[(size_t)b * 197 * 384 + d] = cls_tok[d] + pos[d];
        }
        return;
    }
    bid -= 1152;
    if (bid < 2592) { wt_tile(qkv_w, wQ, 384, 1152, bid, 36, 432, t, tid); return; }
    bid -= 2592;
    if (bid < 864)  { wt_tile(proj_w, wPr, 384, 384, bid, 12, 144, t, tid); return; }
    bid -= 864;
    if (bid < 3456) { wt_tile(fc1_w, wF1, 384, 1536, bid, 48, 576, t, tid); return; }
    bid -= 3456;
    if (bid < 3456) { wt_tile(fc2_w, wF2, 1536, 384, bid, 12, 576, t, tid); return; }
    bid -= 3456;
    if (bid < 9408) {
        int idx = bid * 256 + tid;
        int k = idx % 768, m = idx / 768;
        int b = m / 196, n = m % 196;
        int c = k >> 8, rem = k & 255, i = rem >> 4, j = rem & 15;
        int py = n / 14, px = n % 14;
        Acol[idx] = __float2bfloat16(x[((b * 3 + c) * 224 + py * 16 + i) * 224 + px * 16 + j]);
        return;
    }
    bid -= 9408;                                        // proto normalize (2000 blocks)
    {
        int p = bid;
        int k = tid >> 6, lane = tid & 63;
        float v[6], ss = 0.f;
        #pragma unroll
        for (int i = 0; i < 6; ++i) {
            int d = lane + 64 * i;
            float tv = proto[((size_t)p * 384 + d) * 4 + k];
            v[i] = tv; ss += tv * tv;
        }
        #pragma unroll
        for (int m = 32; m > 0; m >>= 1) ss += __shfl_xor(ss, m);
        float inv = 1.f / fmaxf(sqrtf(ss), 1e-12f);
        #pragma unroll
        for (int i = 0; i < 6; ++i)
            pn[((size_t)p * 4 + k) * 384 + lane + 64 * i] = __float2bfloat16(v[i] * inv);
    }
}

// ---------------------------------------------------------------- patch-embed GEMM + token assembly + ln1[0] partial stats
__global__ __launch_bounds__(256) void k_patch_tok(
    const u16* __restrict__ A, const u16* __restrict__ Bt,
    const float* __restrict__ bias, const float* __restrict__ pos,
    float* __restrict__ tok, float* __restrict__ st1)
{
    const int M = 3136, K = 768;
    __shared__ u16 As[2][128 * 64];
    __shared__ u16 Bs[2][64 * 64];
    const int tid = threadIdx.x;
    const int wid = tid >> 6, lane = tid & 63;
    const int m0 = blockIdx.y * 128, n0 = blockIdx.x * 64;
    const int srow = tid >> 3;
    const int selem = (tid & 7) << 3;
    const int wm = wid * 32;
    const int bx = blockIdx.x;

    // cls-row partial stats for this 64-col slice (tok cls rows from k_prep)
    if (blockIdx.y == 0) {
        for (int b2 = wid; b2 < 16; b2 += 4) {
            float v = tok[(size_t)b2 * 197 * 384 + n0 + lane];
            float sum = v, sq = v * v;
            #pragma unroll
            for (int m = 32; m > 0; m >>= 1) { sum += __shfl_xor(sum, m); sq += __shfl_xor(sq, m); }
            if (lane == 0) {
                st1[(size_t)(b2 * 197) * 12 + bx * 2]     = sum;
                st1[(size_t)(b2 * 197) * 12 + bx * 2 + 1] = sq;
            }
        }
    }

    f32x4 acc[2][4] = {};

    auto stage = [&](int buf, int kb) {
        #pragma unroll
        for (int g = 0; g < 4; ++g) {
            int r = g * 32 + srow;
            int sw = selem ^ ((r & 7) << 3);
            int gr = m0 + r; if (gr > M - 1) gr = M - 1;
            async_copy16(&As[buf][r * 64 + selem], A + (size_t)gr * K + kb + sw);
        }
        #pragma unroll
        for (int g = 0; g < 2; ++g) {
            int r = g * 32 + srow;
            int sw = selem ^ ((r & 7) << 3);
            async_copy16(&Bs[buf][r * 64 + selem], Bt + (size_t)(n0 + r) * K + kb + sw);
        }
    };

    const int nk = K >> 6;
    stage(0, 0);
    __syncthreads();
    for (int t = 0; t < nk; ++t) {
        const int cur = t & 1;
        if (t + 1 < nk) stage(cur ^ 1, (t + 1) << 6);
        #pragma unroll
        for (int ks = 0; ks < 64; ks += 32) {
            const int kk = ks + ((lane >> 4) << 3);
            bf16x8 af[2], bfr[4];
            #pragma unroll
            for (int i = 0; i < 2; ++i) {
                int r = wm + i * 16 + (lane & 15);
                af[i] = *(const bf16x8*)&As[cur][r * 64 + (kk ^ ((r & 7) << 3))];
            }
            #pragma unroll
            for (int j = 0; j < 4; ++j) {
                int r = j * 16 + (lane & 15);
                bfr[j] = *(const bf16x8*)&Bs[cur][r * 64 + (kk ^ ((r & 7) << 3))];
            }
            #pragma unroll
            for (int i = 0; i < 2; ++i)
                #pragma unroll
                for (int j = 0; j < 4; ++j)
                    acc[i][j] = __builtin_amdgcn_mfma_f32_16x16x32_bf16(af[i], bfr[j], acc[i][j], 0, 0, 0);
        }
        __syncthreads();
    }
    const int cl = lane & 15, rg = (lane >> 4) << 2;
    #pragma unroll
    for (int i = 0; i < 2; ++i) {
        #pragma unroll
        for (int r = 0; r < 4; ++r) {
            const int row = m0 + wm + i * 16 + rg + r;
            float psum = 0.f, psq = 0.f;
            int trow = 0;
            if (row < M) {
                int b = row / 196, n = row % 196;
                trow = b * 197 + 1 + n;
                #pragma unroll
                for (int j = 0; j < 4; ++j) {
                    const int col = n0 + j * 16 + cl;
                    float v = acc[i][j][r] + bias[col] + pos[(size_t)(1 + n) * 384 + col];
                    tok[(size_t)trow * 384 + col] = v;
                    psum += v; psq += v * v;
                }
            }
            #pragma unroll
            for (int m = 1; m <= 8; m <<= 1) { psum += __shfl_xor(psum, m); psq += __shfl_xor(psq, m); }
            if (cl == 0 && row < M) {
                st1[(size_t)trow * 12 + bx * 2]     = psum;
                st1[(size_t)trow * 12 + bx * 2 + 1] = psq;
            }
        }
    }
}

// ---------------------------------------------------------------- fused stats-LN + 128x128 GEMM (bf16 out, opt gelu)
// A = LN(tok) from precomputed partial stats; As + Bs both double-buffered, one barrier/K-step.
template<int GELU>
__global__ __launch_bounds__(256) void k_gemm_lnb(
    const float* __restrict__ tokf, const float* __restrict__ stats,
    const float* __restrict__ lns, const float* __restrict__ lnbv,
    const u16* __restrict__ Bt, const float* __restrict__ bias,
    u16* __restrict__ Cb, int N)
{
    __shared__ u16 As[2][128 * 64];
    __shared__ u16 Bs[2][128 * 64];
    __shared__ __align__(16) float sg[384];
    __shared__ __align__(16) float bg[384];
    const int tid = threadIdx.x, wid = tid >> 6, lane = tid & 63;
    const int m0 = blockIdx.y * 128, n0 = blockIdx.x * 128;
    const int srow = tid >> 3, selem = (tid & 7) << 3;
    const int wm = (wid >> 1) * 64, wn = (wid & 1) * 64;

    for (int i = tid; i < 384; i += 256) { sg[i] = lns[i]; bg[i] = lnbv[i]; }

    const int r_ = tid >> 1, half = tid & 1, c0 = half * 32;
    int gr_ = m0 + r_; if (gr_ > MROWS - 1) gr_ = MROWS - 1;
    const float4* sp = (const float4*)(stats + (size_t)gr_ * 12);
    float4 a0 = sp[0], a1 = sp[1], a2 = sp[2];
    float sum = a0.x + a0.z + a1.x + a1.z + a2.x + a2.z;
    float sq  = a0.y + a0.w + a1.y + a1.w + a2.y + a2.w;
    const float mean = sum * (1.f / 384.f);
    const float rstd = rsqrtf(sq * (1.f / 384.f) - mean * mean + 1e-6f);
    const float* arow = tokf + (size_t)gr_ * 384;

    float4 areg[8];
    auto loadA = [&](int kb) {
        #pragma unroll
        for (int c = 0; c < 8; ++c) areg[c] = *(const float4*)(arow + kb + c0 + c * 4);
    };
    auto writeA = [&](int buf, int kb) {
        #pragma unroll
        for (int c = 0; c < 4; ++c) {
            const int colb = kb + c0 + c * 8;
            float4 s0 = *(const float4*)&sg[colb], s1 = *(const float4*)&sg[colb + 4];
            float4 b0 = *(const float4*)&bg[colb], b1 = *(const float4*)&bg[colb + 4];
            float va[8] = {areg[2*c].x, areg[2*c].y, areg[2*c].z, areg[2*c].w,
                           areg[2*c+1].x, areg[2*c+1].y, areg[2*c+1].z, areg[2*c+1].w};
            float ss[8] = {s0.x, s0.y, s0.z, s0.w, s1.x, s1.y, s1.z, s1.w};
            float bb[8] = {b0.x, b0.y, b0.z, b0.w, b1.x, b1.y, b1.z, b1.w};
            bf16x8 pk;
            #pragma unroll
            for (int e = 0; e < 8; ++e)
                pk[e] = (short)f2b((va[e] - mean) * rstd * ss[e] + bb[e]);
            int chunk = (half * 4 + c) ^ (r_ & 7);
            *(bf16x8*)&As[buf][r_ * 64 + chunk * 8] = pk;
        }
    };
    auto stageB = [&](int buf, int kb) {
        #pragma unroll
        for (int g = 0; g < 4; ++g) {
            int r = g * 32 + srow;
            int sw = selem ^ ((r & 7) << 3);
            async_copy16(&Bs[buf][r * 64 + selem], Bt + (size_t)(n0 + r) * 384 + kb + sw);
        }
    };

    f32x4 acc[4][4] = {};
    loadA(0);
    stageB(0, 0);
    __syncthreads();          // sg/bg ready (Bs[0] also drained here)
    writeA(0, 0);
    __syncthreads();          // As[0] visible
    for (int t = 0; t < 6; ++t) {
        const int cur = t & 1;
        if (t < 5) { stageB(cur ^ 1, (t + 1) << 6); loadA((t + 1) << 6); }
        #pragma unroll
        for (int ks = 0; ks < 64; ks += 32) {
            const int kk = ks + ((lane >> 4) << 3);
            bf16x8 af[4], bfr[4];
            #pragma unroll
            for (int i = 0; i < 4; ++i) {
                int r = wm + i * 16 + (lane & 15);
                af[i] = *(const bf16x8*)&As[cur][r * 64 + (kk ^ ((r & 7) << 3))];
            }
            #pragma unroll
            for (int j = 0; j < 4; ++j) {
                int r = wn + j * 16 + (lane & 15);
                bfr[j] = *(const bf16x8*)&Bs[cur][r * 64 + (kk ^ ((r & 7) << 3))];
            }
            #pragma unroll
            for (int i = 0; i < 4; ++i)
                #pragma unroll
                for (int j = 0; j < 4; ++j)
                    acc[i][j] = __builtin_amdgcn_mfma_f32_16x16x32_bf16(af[i], bfr[j], acc[i][j], 0, 0, 0);
        }
        if (t < 5) writeA(cur ^ 1, (t + 1) << 6);   // writes As[next]; current readers done in this thread,
        __syncthreads();                            // other waves protected: they only read As[cur] pre-barrier
    }
    const int cl = lane & 15, rg = (lane >> 4) << 2;
    #pragma unroll
    for (int i = 0; i < 4; ++i) {
        #pragma unroll
        for (int j = 0; j < 4; ++j) {
            const int col = n0 + wn + j * 16 + cl;
            const float bv = bias[col];
            #pragma unroll
            for (int r = 0; r < 4; ++r) {
                const int row = m0 + wm + i * 16 + rg + r;
                if (row >= MROWS) continue;
                float v = acc[i][j][r] + bv;
                if (GELU) v = 0.5f * v * (1.0f + erff(v * 0.70710678118f));
                Cb[(size_t)row * N + col] = f2b(v);
            }
        }
    }
}

// ---------------------------------------------------------------- bf16 MFMA GEMM 128x64, dbuf, +res fp32 in-place, +partial stats
__global__ __launch_bounds__(256) void k_mfma_gemm64(
    const u16* __restrict__ A, const u16* __restrict__ Bt,
    const float* __restrict__ bias, float* __restrict__ tok,
    int M, int K, float* __restrict__ stats)
{
    const int N = 384;
    __shared__ u16 As[2][128 * 64];
    __shared__ u16 Bs[2][64 * 64];
    const int tid = threadIdx.x;
    const int wid = tid >> 6, lane = tid & 63;
    const int m0 = blockIdx.y * 128, n0 = blockIdx.x * 64;
    const int srow = tid >> 3;
    const int selem = (tid & 7) << 3;
    const int wm = wid * 32;
    const int bx = blockIdx.x;

    f32x4 acc[2][4] = {};

    auto stage = [&](int buf, int kb) {
        #pragma unroll
        for (int g = 0; g < 4; ++g) {
            int r = g * 32 + srow;
            int sw = selem ^ ((r & 7) << 3);
            int gr = m0 + r; if (gr > M - 1) gr = M - 1;
            async_copy16(&As[buf][r * 64 + selem], A + (size_t)gr * K + kb + sw);
        }
        #pragma unroll
        for (int g = 0; g < 2; ++g) {
            int r = g * 32 + srow;
            int sw = selem ^ ((r & 7) << 3);
            async_copy16(&Bs[buf][r * 64 + selem], Bt + (size_t)(n0 + r) * K + kb + sw);
        }
    };

    const int nk = K >> 6;
    stage(0, 0);
    __syncthreads();
    for (int t = 0; t < nk; ++t) {
        const int cur = t & 1;
        if (t + 1 < nk) stage(cur ^ 1, (t + 1) << 6);
        #pragma unroll
        for (int ks = 0; ks < 64; ks += 32) {
            const int kk = ks + ((lane >> 4) << 3);
            bf16x8 af[2], bfr[4];
            #pragma unroll
            for (int i = 0; i < 2; ++i) {
                int r = wm + i * 16 + (lane & 15);
                af[i] = *(const bf16x8*)&As[cur][r * 64 + (kk ^ ((r & 7) << 3))];
            }
            #pragma unroll
            for (int j = 0; j < 4; ++j) {
                int r = j * 16 + (lane & 15);
                bfr[j] = *(const bf16x8*)&Bs[cur][r * 64 + (kk ^ ((r & 7) << 3))];
            }
            #pragma unroll
            for (int i = 0; i < 2; ++i)
                #pragma unroll
                for (int j = 0; j < 4; ++j)
                    acc[i][j] = __builtin_amdgcn_mfma_f32_16x16x32_bf16(af[i], bfr[j], acc[i][j], 0, 0, 0);
        }
        __syncthreads();
    }
    const int cl = lane & 15, rg = (lane >> 4) << 2;
    #pragma unroll
    for (int i = 0; i < 2; ++i) {
        #pragma unroll
        for (int r = 0; r < 4; ++r) {
            const int row = m0 + wm + i * 16 + rg + r;
            float psum = 0.f, psq = 0.f;
            if (row < M) {
                #pragma unroll
                for (int j = 0; j < 4; ++j) {
                    const int col = n0 + j * 16 + cl;
                    size_t idx = (size_t)row * N + col;
                    float v = acc[i][j][r] + bias[col] + tok[idx];
                    tok[idx] = v;
                    psum += v; psq += v * v;
                }
            }
            #pragma unroll
            for (int m = 1; m <= 8; m <<= 1) { psum += __shfl_xor(psum, m); psq += __shfl_xor(psq, m); }
            if (cl == 0 && row < M) {
                stats[(size_t)row * 12 + bx * 2]     = psum;
                stats[(size_t)row * 12 + bx * 2 + 1] = psq;
            }
        }
    }
}

// ---------------------------------------------------------------- MFMA attention (proven)
__global__ __launch_bounds__(256) void k_attn_mfma(const u16* __restrict__ qkv, u16* __restrict__ o) {
    __shared__ u16 Ks[208 * 64];
    __shared__ u16 VT[64 * 256];
    __shared__ u16 Pl[4][16 * 256];
    const int bh = blockIdx.x;
    const int b = bh / 6, hh = bh % 6;
    const u16* base = qkv + (size_t)b * 197 * 1152 + hh * 64;
    const int tid = threadIdx.x, wid = tid >> 6, lane = tid & 63;

    for (int i = tid; i < 64 * 59; i += 256) {
        int d = i / 59, k = 197 + i % 59;
        VT[d * 256 + (k ^ ((d & 7) << 3))] = 0;
    }
    for (int i = tid; i < 64 * 48; i += 256) {
        int q = i / 48, k = 208 + i % 48;
        Pl[q >> 4][(q & 15) * 256 + (k ^ ((q & 7) << 3))] = 0;
    }
    for (int i = tid; i < 197 * 8; i += 256) {
        int r = i >> 3, cc = (i & 7) << 3;
        uint4 v = *(const uint4*)(base + (size_t)r * 1152 + 384 + cc);
        *(uint4*)&Ks[r * 64 + (cc ^ ((r & 7) << 3))] = v;
    }
    for (int i = tid; i < 197 * 8; i += 256) {
        int r = i >> 3, d0 = (i & 7) << 3;
        uint4 v = *(const uint4*)(base + (size_t)r * 1152 + 768 + d0);
        const u16* pv = (const u16*)&v;
        #pragma unroll
        for (int j = 0; j < 8; ++j) {
            int d = d0 + j;
            VT[d * 256 + (r ^ ((d & 7) << 3))] = pv[j];
        }
    }
    __syncthreads();

    const int g = lane >> 4, c = lane & 15;
    const int t0 = blockIdx.y * 7;
    const int nt = blockIdx.y ? 6 : 7;
    for (int t = wid; t < nt; t += 4) {
        const int q0 = (t0 + t) * 16;
        int qrow = q0 + c; if (qrow > 196) qrow = 196;
        bf16x8 aq[2];
        aq[0] = *(const bf16x8*)(base + (size_t)qrow * 1152 + g * 8);
        aq[1] = *(const bf16x8*)(base + (size_t)qrow * 1152 + 32 + g * 8);

        f32x4 acc[13] = {};
        #pragma unroll
        for (int j = 0; j < 13; ++j) {
            int kr = j * 16 + c;
            bf16x8 b0 = *(const bf16x8*)&Ks[kr * 64 + ((g * 8) ^ ((kr & 7) << 3))];
            bf16x8 b1 = *(const bf16x8*)&Ks[kr * 64 + ((32 + g * 8) ^ ((kr & 7) << 3))];
            acc[j] = __builtin_amdgcn_mfma_f32_16x16x32_bf16(aq[0], b0, acc[j], 0, 0, 0);
            acc[j] = __builtin_amdgcn_mfma_f32_16x16x32_bf16(aq[1], b1, acc[j], 0, 0, 0);
        }

        float sc[13][4];
        float mr[4] = {-1e30f, -1e30f, -1e30f, -1e30f};
        #pragma unroll
        for (int j = 0; j < 13; ++j) {
            bool valid = (j * 16 + c) < 197;
            #pragma unroll
            for (int r = 0; r < 4; ++r) {
                float v = valid ? acc[j][r] * 0.125f : -1e30f;
                sc[j][r] = v;
                mr[r] = fmaxf(mr[r], v);
            }
        }
        #pragma unroll
        for (int r = 0; r < 4; ++r) {
            #pragma unroll
            for (int msk = 1; msk <= 8; msk <<= 1) mr[r] = fmaxf(mr[r], __shfl_xor(mr[r], msk));
        }
        float lr[4] = {0.f, 0.f, 0.f, 0.f};
        #pragma unroll
        for (int j = 0; j < 13; ++j)
            #pragma unroll
            for (int r = 0; r < 4; ++r) { float e = __expf(sc[j][r] - mr[r]); sc[j][r] = e; lr[r] += e; }
        #pragma unroll
        for (int r = 0; r < 4; ++r) {
            #pragma unroll
            for (int msk = 1; msk <= 8; msk <<= 1) lr[r] += __shfl_xor(lr[r], msk);
            lr[r] = 1.f / lr[r];
        }
        #pragma unroll
        for (int j = 0; j < 13; ++j) {
            int col = j * 16 + c;
            #pragma unroll
            for (int r = 0; r < 4; ++r) {
                int q = g * 4 + r;
                Pl[wid][q * 256 + (col ^ ((q & 7) << 3))] = f2b(sc[j][r] * lr[r]);
            }
        }
        asm volatile("s_waitcnt lgkmcnt(0)" ::: "memory");

        f32x4 av[4] = {};
        #pragma unroll
        for (int ks = 0; ks < 7; ++ks) {
            int kk = ks * 32 + g * 8;
            bf16x8 ap = *(const bf16x8*)&Pl[wid][c * 256 + (kk ^ ((c & 7) << 3))];
            #pragma unroll
            for (int jd = 0; jd < 4; ++jd) {
                int dr = jd * 16 + c;
                bf16x8 bv = *(const bf16x8*)&VT[dr * 256 + (kk ^ ((dr & 7) << 3))];
                av[jd] = __builtin_amdgcn_mfma_f32_16x16x32_bf16(ap, bv, av[jd], 0, 0, 0);
            }
        }
        #pragma unroll
        for (int jd = 0; jd < 4; ++jd) {
            #pragma unroll
            for (int r = 0; r < 4; ++r) {
                int q = q0 + g * 4 + r;
                if (q < 197)
                    o[((size_t)b * 197 + q) * 384 + hh * 64 + jd * 16 + c] = f2b(av[jd][r]);
            }
        }
    }
}

// ---------------------------------------------------------------- final LN + cls out + feature normalize
__device__ __forceinline__ void lnvals(const float* __restrict__ x, const float* __restrict__ s,
                                       const float* __restrict__ bb, int lane, float* v) {
    float sum = 0.f, sq = 0.f;
    #pragma unroll
    for (int i = 0; i < 6; ++i) { float t = x[lane + 64 * i]; v[i] = t; sum += t; sq += t * t; }
    #pragma unroll
    for (int m = 32; m > 0; m >>= 1) { sum += __shfl_xor(sum, m); sq += __shfl_xor(sq, m); }
    float mean = sum * (1.f / 384.f);
    float var  = sq * (1.f / 384.f) - mean * mean;
    float rstd = rsqrtf(var + 1e-6f);
    #pragma unroll
    for (int i = 0; i < 6; ++i) {
        int d = lane + 64 * i;
        v[i] = (v[i] - mean) * rstd * s[d] + bb[d];
    }
}

__global__ __launch_bounds__(256) void k_fnln(const float* __restrict__ tok, const float* __restrict__ s,
                                              const float* __restrict__ bb, u16* __restrict__ fnb,
                                              float* __restrict__ out) {
    int wid = threadIdx.x >> 6, lane = threadIdx.x & 63;
    int row = blockIdx.x * 4 + wid;   // < 3152
    int b = row / 197, t = row % 197;
    float v1[6];
    lnvals(tok + (size_t)row * 384, s, bb, lane, v1);
    if (t == 0) {
        #pragma unroll
        for (int i = 0; i < 6; ++i) out[(size_t)b * 384 + lane + 64 * i] = v1[i];
    } else {
        float v0[6];
        lnvals(tok + (size_t)b * 197 * 384, s, bb, lane, v0);
        float d[6], ss = 0.f;
        #pragma unroll
        for (int i = 0; i < 6; ++i) { d[i] = v1[i] - v0[i]; ss += d[i] * d[i]; }
        #pragma unroll
        for (int m = 32; m > 0; m >>= 1) ss += __shfl_xor(ss, m);
        float inv = 1.f / fmaxf(sqrtf(ss), 1e-12f);
        #pragma unroll
        for (int i = 0; i < 6; ++i)
            fnb[((size_t)b * 196 + t - 1) * 384 + lane + 64 * i] = f2b(d[i] * inv);
    }
}

// ---------------------------------------------------------------- dist: dbuf (both operands) + bijective XCD swizzle
__device__ __forceinline__ void top4_insert(float v, float& t0, float& t1, float& t2, float& t3) {
    if (v > t3) {
        t3 = v;
        if (t3 > t2) { float t = t2; t2 = t3; t3 = t; }
        if (t2 > t1) { float t = t1; t1 = t2; t2 = t; }
        if (t1 > t0) { float t = t0; t0 = t1; t1 = t; }
    }
}

__global__ __launch_bounds__(256) void k_dist_mfma(
    const __hip_bfloat16* __restrict__ fnb, const __hip_bfloat16* __restrict__ pnb,
    const float* __restrict__ psel, float* __restrict__ out)
{
    __shared__ u16 Ap[2][128 * 64];
    __shared__ u16 Bf[2][208 * 64];
    const u16* fn = (const u16*)fnb;
    const u16* pn = (const u16*)pnb;
    const int wg = blockIdx.x;
    const int swz = (wg & 7) * 126 + (wg >> 3);   // bijective: 1008 = 8*126
    const int b = swz & 15, pb = swz >> 4;
    const int tid = threadIdx.x, wid = tid >> 6, lane = tid & 63;
    const int srow = tid >> 3;
    const int selem = (tid & 7) << 3;

    auto stage = [&](int buf, int kt) {
        #pragma unroll
        for (int g = 0; g < 4; ++g) {
            int r = g * 32 + srow;
            int gr = pb * 128 + r; if (gr > 7999) gr = 7999;
            async_copy16(&Ap[buf][r * 64 + selem],
                         pn + (size_t)gr * 384 + kt + (selem ^ ((r & 7) << 3)));
        }
        #pragma unroll
        for (int g = 0; g < 7; ++g) {
            int r = g * 32 + srow;
            if (r < 208) {
                int fr = r > 195 ? 195 : r;
                async_copy16(&Bf[buf][r * 64 + selem],
                             fn + ((size_t)b * 196 + fr) * 384 + kt + (selem ^ ((r & 7) << 3)));
            }
        }
    };

    f32x4 acc[2][13] = {};
    const int cl = lane & 15;

    stage(0, 0);
    __syncthreads();
    for (int kt = 0; kt < 6; ++kt) {
        const int cur = kt & 1;
        if (kt < 5) stage(cur ^ 1, (kt + 1) << 6);
        #pragma unroll
        for (int ks = 0; ks < 64; ks += 32) {
            const int kk = ks + ((lane >> 4) << 3);
            bf16x8 af[2];
            #pragma unroll
            for (int i = 0; i < 2; ++i) {
                int r = wid * 32 + i * 16 + cl;
                af[i] = *(const bf16x8*)&Ap[cur][r * 64 + (kk ^ ((r & 7) << 3))];
            }
            #pragma unroll
            for (int j = 0; j < 13; ++j) {
                int r = j * 16 + cl;
                bf16x8 bj = *(const bf16x8*)&Bf[cur][r * 64 + (kk ^ ((r & 7) << 3))];
                acc[0][j] = __builtin_amdgcn_mfma_f32_16x16x32_bf16(af[0], bj, acc[0][j], 0, 0, 0);
                acc[1][j] = __builtin_amdgcn_mfma_f32_16x16x32_bf16(af[1], bj, acc[1][j], 0, 0, 0);
            }
        }
        __syncthreads();
    }
    #pragma unroll
    for (int mi = 0; mi < 2; ++mi) {
        float t0 = -1e30f, t1 = -1e30f, t2 = -1e30f, t3 = -1e30f;
        #pragma unroll
        for (int j = 0; j < 13; ++j) {
            if (j * 16 + cl >= 196) continue;
            #pragma unroll
            for (int r = 0; r < 4; ++r) top4_insert(acc[mi][j][r], t0, t1, t2, t3);
        }
        #pragma unroll
        for (int m = 1; m <= 8; m <<= 1) {
            float u0 = __shfl_xor(t0, m), u1 = __shfl_xor(t1, m);
            float u2 = __shfl_xor(t2, m), u3 = __shfl_xor(t3, m);
            top4_insert(u0, t0, t1, t2, t3);
            top4_insert(u1, t0, t1, t2, t3);
            top4_insert(u2, t0, t1, t2, t3);
            top4_insert(u3, t0, t1, t2, t3);
        }
        if (cl == 0) {
            int proto = pb * 32 + wid * 8 + mi * 4 + (lane >> 4);
            if (proto < 2000) {
                float sl[4], fac = 1e-10f;
                #pragma unroll
                for (int i = 0; i < 4; ++i) {
                    sl[i] = 1.f / (1.f + expf(-psel[proto * 4 + i] * 100.f));
                    fac += sl[i];
                }
                float score = (t0 * sl[0] + t1 * sl[1] + t2 * sl[2] + t3 * sl[3]) * 4.f / fac;
                out[6144 + (size_t)b * 2000 + proto] = score;
            }
        }
    }
}

// ---------------------------------------------------------------- host launcher
extern "C" void kernel_launch(void* const* d_in, const int* in_sizes, int n_in,
                              void* d_out, int out_size, void* d_ws, size_t ws_size,
                              hipStream_t stream) {
    const float* x       = (const float*)d_in[0];
    const float* patch_w = (const float*)d_in[1];
    const float* patch_b = (const float*)d_in[2];
    const float* cls_tok = (const float*)d_in[3];
    const float* pos     = (const float*)d_in[4];
    const float* ln1_s   = (const float*)d_in[5];
    const float* ln1_b   = (const float*)d_in[6];
    const float* qkv_w   = (const float*)d_in[7];
    const float* qkv_b   = (const float*)d_in[8];
    const float* proj_w  = (const float*)d_in[9];
    const float* proj_b  = (const float*)d_in[10];
    const float* ln2_s   = (const float*)d_in[11];
    const float* ln2_b   = (const float*)d_in[12];
    const float* fc1_w   = (const float*)d_in[13];
    const float* fc1_b   = (const float*)d_in[14];
    const float* fc2_w   = (const float*)d_in[15];
    const float* fc2_b   = (const float*)d_in[16];
    const float* norm_s  = (const float*)d_in[17];
    const float* norm_b  = (const float*)d_in[18];
    const float* proto   = (const float*)d_in[19];
    const float* psel    = (const float*)d_in[20];
    float* out = (float*)d_out;
    char* w = (char*)d_ws;

    __hip_bfloat16* wPb  = (__hip_bfloat16*)(w);             // 589824
    u16*            wQ   = (u16*)(w + 589824);               // 5308416
    u16*            wPr  = (u16*)(w + 5898240);              // 1769472
    u16*            wF1  = (u16*)(w + 7667712);              // 7077888
    u16*            wF2  = (u16*)(w + 14745600);             // 7077888
    __hip_bfloat16* Acol = (__hip_bfloat16*)(w + 21823488);  // 4816896
    float*          tok  = (float*)         (w + 31457280);  // 4841472
    float*          st1  = (float*)         (w + 36298752);  // 3152*12*4 = 151296
    float*          st2  = (float*)         (w + 36450048);  // 151296
    u16*            qkvb = (u16*)(w + 38719488);             // 7262208
    u16*            aob  = (u16*)(w + 53243904);             // 2420736
    u16*            hbig = (u16*)(w + 55664640);             // 9682944
    u16*            fnb  = (u16*)(w + 70189056);             // 2408448
    __hip_bfloat16* pnb  = (__hip_bfloat16*)(w + 72597504);  // 6144000

    k_prep<<<22928, 256, 0, stream>>>(patch_w, wPb, cls_tok, pos, tok,
                                      qkv_w, (__hip_bfloat16*)wQ,
                                      proj_w, (__hip_bfloat16*)wPr,
                                      fc1_w, (__hip_bfloat16*)wF1,
                                      fc2_w, (__hip_bfloat16*)wF2,
                                      x, Acol, proto, pnb);
    k_patch_tok<<<dim3(6, 25), 256, 0, stream>>>((const u16*)Acol, (const u16*)wPb,
                                                 patch_b, pos, tok, st1);

    for (int l = 0; l < 6; ++l) {
        k_gemm_lnb<0><<<dim3(9, 25), 256, 0, stream>>>(
            tok, st1, ln1_s + l * 384, ln1_b + l * 384,
            wQ + (size_t)l * 1152 * 384, qkv_b + l * 1152, qkvb, 1152);
        k_attn_mfma<<<dim3(96, 2), 256, 0, stream>>>(qkvb, aob);
        k_mfma_gemm64<<<dim3(6, 25), 256, 0, stream>>>(
            aob, wPr + (size_t)l * 384 * 384, proj_b + l * 384, tok, MROWS, 384, st2);
        k_gemm_lnb<1><<<dim3(12, 25), 256, 0, stream>>>(
            tok, st2, ln2_s + l * 384, ln2_b + l * 384,
            wF1 + (size_t)l * 384 * 1536, fc1_b + l * 1536, hbig, 1536);
        k_mfma_gemm64<<<dim3(6, 25), 256, 0, stream>>>(
            hbig, wF2 + (size_t)l * 1536 * 384, fc2_b + l * 384, tok, MROWS, 1536, st1);
    }

    k_fnln<<<788, 256, 0, stream>>>(tok, norm_s, norm_b, fnb, out);
    k_dist_mfma<<<1008, 256, 0, stream>>>((const __hip_bfloat16*)fnb, pnb, psel, out);
}

// Round 15
// 591.018 us; speedup vs baseline: 1.2203x; 1.2203x over previous
//
#include <hip/hip_runtime.h>
#include <hip/hip_bf16.h>
#include <math.h>

// ProtoViT forward: bf16-MFMA GEMMs (128x64 tiles, dbuf, both-sides swizzle) +
// MFMA attention, merged prep, XCD-swizzled dist with 64-row blocks.
// B=16, D=384, DEPTH=6, H=6, HD=64, P=2000, NP=4, N=196, T=197.

#define MROWS 3152   // 16*197

typedef short bf16x8 __attribute__((ext_vector_type(8)));
typedef float f32x4 __attribute__((ext_vector_type(4)));
typedef unsigned short u16;

__device__ __forceinline__ void async_copy16(void* lds, const void* g) {
    __builtin_amdgcn_global_load_lds((const __attribute__((address_space(1))) unsigned int*)g,
                                     (__attribute__((address_space(3))) unsigned int*)lds,
                                     16, 0, 0);
}

__device__ __forceinline__ u16 f2b(float x) {
    __hip_bfloat16 h = __float2bfloat16(x);
    return *(u16*)&h;
}

// ---------------------------------------------------------------- merged prep kernel
__device__ __forceinline__ void wt_tile(const float* __restrict__ W, __hip_bfloat16* __restrict__ Wt,
                                        int K, int N, int id, int ntx, int perlayer,
                                        float (*t)[33], int tid) {
    int z = id / perlayer, rem = id % perlayer;
    int n0 = (rem % ntx) * 32, k0 = (rem / ntx) * 32;
    const float* src = W + (size_t)z * K * N;
    __hip_bfloat16* dst = Wt + (size_t)z * K * N;
    int tx = tid & 31, ty = tid >> 5;
    #pragma unroll
    for (int i = 0; i < 4; ++i) t[ty + i * 8][tx] = src[(size_t)(k0 + ty + i * 8) * N + n0 + tx];
    __syncthreads();
    #pragma unroll
    for (int i = 0; i < 4; ++i)
        dst[(size_t)(n0 + ty + i * 8) * K + k0 + tx] = __float2bfloat16(t[tx][ty + i * 8]);
}

__global__ __launch_bounds__(256) void k_prep(
    const float* __restrict__ patch_w, __hip_bfloat16* __restrict__ wPb,
    const float* __restrict__ cls_tok, const float* __restrict__ pos, float* __restrict__ tok,
    const float* __restrict__ qkv_w, __hip_bfloat16* __restrict__ wQ,
    const float* __restrict__ proj_w, __hip_bfloat16* __restrict__ wPr,
    const float* __restrict__ fc1_w, __hip_bfloat16* __restrict__ wF1,
    const float* __restrict__ fc2_w, __hip_bfloat16* __restrict__ wF2,
    const float* __restrict__ x, __hip_bfloat16* __restrict__ Acol,
    const float* __restrict__ proto, __hip_bfloat16* __restrict__ pn)
{
    __shared__ float t[32][33];
    int bid = blockIdx.x;
    const int tid = threadIdx.x;
    if (bid < 1152) {
        int i = bid * 256 + tid;
        wPb[i] = __float2bfloat16(patch_w[i]);
        if (i < 6144) {
            int b = i / 384, d = i % 384;
            tok[(size_t)b * 197 * 384 + d] = cls_tok[d] + pos[d];
        }
        return;
    }
    bid -= 1152;
    if (bid < 2592) { wt_tile(qkv_w, wQ, 384, 1152, bid, 36, 432, t, tid); return; }
    bid -= 2592;
    if (bid < 864)  { wt_tile(proj_w, wPr, 384, 384, bid, 12, 144, t, tid); return; }
    bid -= 864;
    if (bid < 3456) { wt_tile(fc1_w, wF1, 384, 1536, bid, 48, 576, t, tid); return; }
    bid -= 3456;
    if (bid < 3456) { wt_tile(fc2_w, wF2, 1536, 384, bid, 12, 576, t, tid); return; }
    bid -= 3456;
    if (bid < 9408) {
        int idx = bid * 256 + tid;
        int k = idx % 768, m = idx / 768;
        int b = m / 196, n = m % 196;
        int c = k >> 8, rem = k & 255, i = rem >> 4, j = rem & 15;
        int py = n / 14, px = n % 14;
        Acol[idx] = __float2bfloat16(x[((b * 3 + c) * 224 + py * 16 + i) * 224 + px * 16 + j]);
        return;
    }
    bid -= 9408;                                        // proto normalize (2000 blocks)
    {
        int p = bid;
        int k = tid >> 6, lane = tid & 63;
        float v[6], ss = 0.f;
        #pragma unroll
        for (int i = 0; i < 6; ++i) {
            int d = lane + 64 * i;
            float tv = proto[((size_t)p * 384 + d) * 4 + k];
            v[i] = tv; ss += tv * tv;
        }
        #pragma unroll
        for (int m = 32; m > 0; m >>= 1) ss += __shfl_xor(ss, m);
        float inv = 1.f / fmaxf(sqrtf(ss), 1e-12f);
        #pragma unroll
        for (int i = 0; i < 6; ++i)
            pn[((size_t)p * 4 + k) * 384 + lane + 64 * i] = __float2bfloat16(v[i] * inv);
    }
}

// ---------------------------------------------------------------- patch-embed GEMM + token assembly
__global__ __launch_bounds__(256) void k_patch_tok(
    const u16* __restrict__ A, const u16* __restrict__ Bt,
    const float* __restrict__ bias, const float* __restrict__ pos,
    float* __restrict__ tok)
{
    const int M = 3136, K = 768;
    __shared__ u16 As[2][128 * 64];
    __shared__ u16 Bs[2][64 * 64];
    const int tid = threadIdx.x;
    const int wid = tid >> 6, lane = tid & 63;
    const int m0 = blockIdx.y * 128, n0 = blockIdx.x * 64;
    const int srow = tid >> 3;
    const int selem = (tid & 7) << 3;
    const int wm = wid * 32;

    f32x4 acc[2][4] = {};

    auto stage = [&](int buf, int kb) {
        #pragma unroll
        for (int g = 0; g < 4; ++g) {
            int r = g * 32 + srow;
            int sw = selem ^ ((r & 7) << 3);
            int gr = m0 + r; if (gr > M - 1) gr = M - 1;
            async_copy16(&As[buf][r * 64 + selem], A + (size_t)gr * K + kb + sw);
        }
        #pragma unroll
        for (int g = 0; g < 2; ++g) {
            int r = g * 32 + srow;
            int sw = selem ^ ((r & 7) << 3);
            async_copy16(&Bs[buf][r * 64 + selem], Bt + (size_t)(n0 + r) * K + kb + sw);
        }
    };

    const int nk = K >> 6;
    stage(0, 0);
    __syncthreads();
    for (int t = 0; t < nk; ++t) {
        const int cur = t & 1;
        if (t + 1 < nk) stage(cur ^ 1, (t + 1) << 6);
        #pragma unroll
        for (int ks = 0; ks < 64; ks += 32) {
            const int kk = ks + ((lane >> 4) << 3);
            bf16x8 af[2], bfr[4];
            #pragma unroll
            for (int i = 0; i < 2; ++i) {
                int r = wm + i * 16 + (lane & 15);
                af[i] = *(const bf16x8*)&As[cur][r * 64 + (kk ^ ((r & 7) << 3))];
            }
            #pragma unroll
            for (int j = 0; j < 4; ++j) {
                int r = j * 16 + (lane & 15);
                bfr[j] = *(const bf16x8*)&Bs[cur][r * 64 + (kk ^ ((r & 7) << 3))];
            }
            #pragma unroll
            for (int i = 0; i < 2; ++i)
                #pragma unroll
                for (int j = 0; j < 4; ++j)
                    acc[i][j] = __builtin_amdgcn_mfma_f32_16x16x32_bf16(af[i], bfr[j], acc[i][j], 0, 0, 0);
        }
        __syncthreads();
    }
    const int cl = lane & 15, rg = (lane >> 4) << 2;
    #pragma unroll
    for (int i = 0; i < 2; ++i) {
        #pragma unroll
        for (int j = 0; j < 4; ++j) {
            const int col = n0 + j * 16 + cl;
            const float bv = bias[col];
            #pragma unroll
            for (int r = 0; r < 4; ++r) {
                const int row = m0 + wm + i * 16 + rg + r;
                if (row >= M) continue;
                int b = row / 196, n = row % 196;
                float v = acc[i][j][r] + bv + pos[(size_t)(1 + n) * 384 + col];
                tok[((size_t)b * 197 + 1 + n) * 384 + col] = v;
            }
        }
    }
}

// ---------------------------------------------------------------- layernorm (fp32 compute), bf16 out
__global__ __launch_bounds__(256) void k_ln(const float* __restrict__ X, const float* __restrict__ s,
                                            const float* __restrict__ bb, u16* __restrict__ Y) {
    int wid = threadIdx.x >> 6, lane = threadIdx.x & 63;
    int row = blockIdx.x * 4 + wid;
    if (row >= MROWS) return;
    const float* x = X + (size_t)row * 384;
    float v[6], sum = 0.f, sq = 0.f;
    #pragma unroll
    for (int i = 0; i < 6; ++i) { float t = x[lane + 64 * i]; v[i] = t; sum += t; sq += t * t; }
    #pragma unroll
    for (int m = 32; m > 0; m >>= 1) { sum += __shfl_xor(sum, m); sq += __shfl_xor(sq, m); }
    float mean = sum * (1.f / 384.f);
    float var  = sq * (1.f / 384.f) - mean * mean;
    float rstd = rsqrtf(var + 1e-6f);
    u16* y = Y + (size_t)row * 384;
    #pragma unroll
    for (int i = 0; i < 6; ++i) {
        int d = lane + 64 * i;
        y[d] = f2b((v[i] - mean) * rstd * s[d] + bb[d]);
    }
}

// ---------------------------------------------------------------- bf16 MFMA GEMM, 128x64 tile, dbuf, swizzled
template<int RES, int GELU, int BF16OUT>
__global__ __launch_bounds__(256) void k_mfma_gemm64(
    const u16* __restrict__ A, const u16* __restrict__ Bt,
    const float* __restrict__ bias, const float* __restrict__ res,
    float* __restrict__ Cf, __hip_bfloat16* __restrict__ Cb,
    int M, int N, int K)
{
    __shared__ u16 As[2][128 * 64];
    __shared__ u16 Bs[2][64 * 64];
    const int tid = threadIdx.x;
    const int wid = tid >> 6, lane = tid & 63;
    const int m0 = blockIdx.y * 128, n0 = blockIdx.x * 64;
    const int srow = tid >> 3;
    const int selem = (tid & 7) << 3;
    const int wm = wid * 32;

    f32x4 acc[2][4] = {};

    auto stage = [&](int buf, int kb) {
        #pragma unroll
        for (int g = 0; g < 4; ++g) {
            int r = g * 32 + srow;
            int sw = selem ^ ((r & 7) << 3);
            int gr = m0 + r; if (gr > M - 1) gr = M - 1;
            async_copy16(&As[buf][r * 64 + selem], A + (size_t)gr * K + kb + sw);
        }
        #pragma unroll
        for (int g = 0; g < 2; ++g) {
            int r = g * 32 + srow;
            int sw = selem ^ ((r & 7) << 3);
            async_copy16(&Bs[buf][r * 64 + selem], Bt + (size_t)(n0 + r) * K + kb + sw);
        }
    };

    const int nk = K >> 6;
    stage(0, 0);
    __syncthreads();
    for (int t = 0; t < nk; ++t) {
        const int cur = t & 1;
        if (t + 1 < nk) stage(cur ^ 1, (t + 1) << 6);
        #pragma unroll
        for (int ks = 0; ks < 64; ks += 32) {
            const int kk = ks + ((lane >> 4) << 3);
            bf16x8 af[2], bfr[4];
            #pragma unroll
            for (int i = 0; i < 2; ++i) {
                int r = wm + i * 16 + (lane & 15);
                af[i] = *(const bf16x8*)&As[cur][r * 64 + (kk ^ ((r & 7) << 3))];
            }
            #pragma unroll
            for (int j = 0; j < 4; ++j) {
                int r = j * 16 + (lane & 15);
                bfr[j] = *(const bf16x8*)&Bs[cur][r * 64 + (kk ^ ((r & 7) << 3))];
            }
            #pragma unroll
            for (int i = 0; i < 2; ++i)
                #pragma unroll
                for (int j = 0; j < 4; ++j)
                    acc[i][j] = __builtin_amdgcn_mfma_f32_16x16x32_bf16(af[i], bfr[j], acc[i][j], 0, 0, 0);
        }
        __syncthreads();
    }
    const int cl = lane & 15, rg = (lane >> 4) << 2;
    #pragma unroll
    for (int i = 0; i < 2; ++i) {
        #pragma unroll
        for (int j = 0; j < 4; ++j) {
            const int col = n0 + j * 16 + cl;
            const float bv = bias[col];
            #pragma unroll
            for (int r = 0; r < 4; ++r) {
                const int row = m0 + wm + i * 16 + rg + r;
                if (row >= M) continue;
                float v = acc[i][j][r] + bv;
                if (RES) v += res[(size_t)row * N + col];
                if (GELU) v = 0.5f * v * (1.0f + erff(v * 0.70710678118f));
                if (BF16OUT) Cb[(size_t)row * N + col] = __float2bfloat16(v);
                else         Cf[(size_t)row * N + col] = v;
            }
        }
    }
}

// ---------------------------------------------------------------- MFMA attention (proven)
__global__ __launch_bounds__(256) void k_attn_mfma(const u16* __restrict__ qkv, u16* __restrict__ o) {
    __shared__ u16 Ks[208 * 64];
    __shared__ u16 VT[64 * 256];
    __shared__ u16 Pl[4][16 * 256];
    const int bh = blockIdx.x;
    const int b = bh / 6, hh = bh % 6;
    const u16* base = qkv + (size_t)b * 197 * 1152 + hh * 64;
    const int tid = threadIdx.x, wid = tid >> 6, lane = tid & 63;

    for (int i = tid; i < 64 * 59; i += 256) {
        int d = i / 59, k = 197 + i % 59;
        VT[d * 256 + (k ^ ((d & 7) << 3))] = 0;
    }
    for (int i = tid; i < 64 * 48; i += 256) {
        int q = i / 48, k = 208 + i % 48;
        Pl[q >> 4][(q & 15) * 256 + (k ^ ((q & 7) << 3))] = 0;
    }
    for (int i = tid; i < 197 * 8; i += 256) {
        int r = i >> 3, cc = (i & 7) << 3;
        uint4 v = *(const uint4*)(base + (size_t)r * 1152 + 384 + cc);
        *(uint4*)&Ks[r * 64 + (cc ^ ((r & 7) << 3))] = v;
    }
    for (int i = tid; i < 197 * 8; i += 256) {
        int r = i >> 3, d0 = (i & 7) << 3;
        uint4 v = *(const uint4*)(base + (size_t)r * 1152 + 768 + d0);
        const u16* pv = (const u16*)&v;
        #pragma unroll
        for (int j = 0; j < 8; ++j) {
            int d = d0 + j;
            VT[d * 256 + (r ^ ((d & 7) << 3))] = pv[j];
        }
    }
    __syncthreads();

    const int g = lane >> 4, c = lane & 15;
    const int t0 = blockIdx.y * 7;
    const int nt = blockIdx.y ? 6 : 7;
    for (int t = wid; t < nt; t += 4) {
        const int q0 = (t0 + t) * 16;
        int qrow = q0 + c; if (qrow > 196) qrow = 196;
        bf16x8 aq[2];
        aq[0] = *(const bf16x8*)(base + (size_t)qrow * 1152 + g * 8);
        aq[1] = *(const bf16x8*)(base + (size_t)qrow * 1152 + 32 + g * 8);

        f32x4 acc[13] = {};
        #pragma unroll
        for (int j = 0; j < 13; ++j) {
            int kr = j * 16 + c;
            bf16x8 b0 = *(const bf16x8*)&Ks[kr * 64 + ((g * 8) ^ ((kr & 7) << 3))];
            bf16x8 b1 = *(const bf16x8*)&Ks[kr * 64 + ((32 + g * 8) ^ ((kr & 7) << 3))];
            acc[j] = __builtin_amdgcn_mfma_f32_16x16x32_bf16(aq[0], b0, acc[j], 0, 0, 0);
            acc[j] = __builtin_amdgcn_mfma_f32_16x16x32_bf16(aq[1], b1, acc[j], 0, 0, 0);
        }

        float sc[13][4];
        float mr[4] = {-1e30f, -1e30f, -1e30f, -1e30f};
        #pragma unroll
        for (int j = 0; j < 13; ++j) {
            bool valid = (j * 16 + c) < 197;
            #pragma unroll
            for (int r = 0; r < 4; ++r) {
                float v = valid ? acc[j][r] * 0.125f : -1e30f;
                sc[j][r] = v;
                mr[r] = fmaxf(mr[r], v);
            }
        }
        #pragma unroll
        for (int r = 0; r < 4; ++r) {
            #pragma unroll
            for (int msk = 1; msk <= 8; msk <<= 1) mr[r] = fmaxf(mr[r], __shfl_xor(mr[r], msk));
        }
        float lr[4] = {0.f, 0.f, 0.f, 0.f};
        #pragma unroll
        for (int j = 0; j < 13; ++j)
            #pragma unroll
            for (int r = 0; r < 4; ++r) { float e = __expf(sc[j][r] - mr[r]); sc[j][r] = e; lr[r] += e; }
        #pragma unroll
        for (int r = 0; r < 4; ++r) {
            #pragma unroll
            for (int msk = 1; msk <= 8; msk <<= 1) lr[r] += __shfl_xor(lr[r], msk);
            lr[r] = 1.f / lr[r];
        }
        #pragma unroll
        for (int j = 0; j < 13; ++j) {
            int col = j * 16 + c;
            #pragma unroll
            for (int r = 0; r < 4; ++r) {
                int q = g * 4 + r;
                Pl[wid][q * 256 + (col ^ ((q & 7) << 3))] = f2b(sc[j][r] * lr[r]);
            }
        }
        asm volatile("s_waitcnt lgkmcnt(0)" ::: "memory");

        f32x4 av[4] = {};
        #pragma unroll
        for (int ks = 0; ks < 7; ++ks) {
            int kk = ks * 32 + g * 8;
            bf16x8 ap = *(const bf16x8*)&Pl[wid][c * 256 + (kk ^ ((c & 7) << 3))];
            #pragma unroll
            for (int jd = 0; jd < 4; ++jd) {
                int dr = jd * 16 + c;
                bf16x8 bv = *(const bf16x8*)&VT[dr * 256 + (kk ^ ((dr & 7) << 3))];
                av[jd] = __builtin_amdgcn_mfma_f32_16x16x32_bf16(ap, bv, av[jd], 0, 0, 0);
            }
        }
        #pragma unroll
        for (int jd = 0; jd < 4; ++jd) {
            #pragma unroll
            for (int r = 0; r < 4; ++r) {
                int q = q0 + g * 4 + r;
                if (q < 197)
                    o[((size_t)b * 197 + q) * 384 + hh * 64 + jd * 16 + c] = f2b(av[jd][r]);
            }
        }
    }
}

// ---------------------------------------------------------------- final LN + cls out + feature normalize
__device__ __forceinline__ void lnvals(const float* __restrict__ x, const float* __restrict__ s,
                                       const float* __restrict__ bb, int lane, float* v) {
    float sum = 0.f, sq = 0.f;
    #pragma unroll
    for (int i = 0; i < 6; ++i) { float t = x[lane + 64 * i]; v[i] = t; sum += t; sq += t * t; }
    #pragma unroll
    for (int m = 32; m > 0; m >>= 1) { sum += __shfl_xor(sum, m); sq += __shfl_xor(sq, m); }
    float mean = sum * (1.f / 384.f);
    float var  = sq * (1.f / 384.f) - mean * mean;
    float rstd = rsqrtf(var + 1e-6f);
    #pragma unroll
    for (int i = 0; i < 6; ++i) {
        int d = lane + 64 * i;
        v[i] = (v[i] - mean) * rstd * s[d] + bb[d];
    }
}

__global__ __launch_bounds__(256) void k_fnln(const float* __restrict__ tok, const float* __restrict__ s,
                                              const float* __restrict__ bb, u16* __restrict__ fnb,
                                              float* __restrict__ out) {
    int wid = threadIdx.x >> 6, lane = threadIdx.x & 63;
    int row = blockIdx.x * 4 + wid;   // < 3152
    int b = row / 197, t = row % 197;
    float v1[6];
    lnvals(tok + (size_t)row * 384, s, bb, lane, v1);
    if (t == 0) {
        #pragma unroll
        for (int i = 0; i < 6; ++i) out[(size_t)b * 384 + lane + 64 * i] = v1[i];
    } else {
        float v0[6];
        lnvals(tok + (size_t)b * 197 * 384, s, bb, lane, v0);
        float d[6], ss = 0.f;
        #pragma unroll
        for (int i = 0; i < 6; ++i) { d[i] = v1[i] - v0[i]; ss += d[i] * d[i]; }
        #pragma unroll
        for (int m = 32; m > 0; m >>= 1) ss += __shfl_xor(ss, m);
        float inv = 1.f / fmaxf(sqrtf(ss), 1e-12f);
        #pragma unroll
        for (int i = 0; i < 6; ++i)
            fnb[((size_t)b * 196 + t - 1) * 384 + lane + 64 * i] = f2b(d[i] * inv);
    }
}

// ---------------------------------------------------------------- dist: 64-proto-row blocks, XCD swizzle, single-buffer
__device__ __forceinline__ void top4_insert(float v, float& t0, float& t1, float& t2, float& t3) {
    if (v > t3) {
        t3 = v;
        if (t3 > t2) { float t = t2; t2 = t3; t3 = t; }
        if (t2 > t1) { float t = t1; t1 = t2; t2 = t; }
        if (t1 > t0) { float t = t0; t0 = t1; t1 = t; }
    }
}

__global__ __launch_bounds__(256) void k_dist_mfma(
    const __hip_bfloat16* __restrict__ fnb, const __hip_bfloat16* __restrict__ pnb,
    const float* __restrict__ psel, float* __restrict__ out)
{
    __shared__ u16 Ap[64 * 64];
    __shared__ u16 Bf[208 * 64];
    const u16* fn = (const u16*)fnb;
    const u16* pn = (const u16*)pnb;
    // bijective XCD swizzle: 2016 = 8*252; same-XCD blocks share a small pb range
    const int wg = blockIdx.x;
    const int swz = (wg & 7) * 252 + (wg >> 3);
    const int b = swz & 15, pb = swz >> 4;      // pb in [0,126): 64 proto-rows each
    const int tid = threadIdx.x, wid = tid >> 6, lane = tid & 63;
    const int srow = tid >> 3;
    const int selem = (tid & 7) << 3;

    f32x4 acc[13] = {};

    for (int kt = 0; kt < 384; kt += 64) {
        __syncthreads();
        #pragma unroll
        for (int g = 0; g < 2; ++g) {
            int r = g * 32 + srow;
            int gr = pb * 64 + r; if (gr > 7999) gr = 7999;
            async_copy16(&Ap[r * 64 + selem],
                         pn + (size_t)gr * 384 + kt + (selem ^ ((r & 7) << 3)));
        }
        #pragma unroll
        for (int g = 0; g < 7; ++g) {
            int r = g * 32 + srow;
            if (r < 208) {
                int fr = r > 195 ? 195 : r;
                async_copy16(&Bf[r * 64 + selem],
                             fn + ((size_t)b * 196 + fr) * 384 + kt + (selem ^ ((r & 7) << 3)));
            }
        }
        __syncthreads();
        #pragma unroll
        for (int ks = 0; ks < 64; ks += 32) {
            const int kk = ks + ((lane >> 4) << 3);
            bf16x8 af;
            {
                int r = wid * 16 + (lane & 15);
                af = *(const bf16x8*)&Ap[r * 64 + (kk ^ ((r & 7) << 3))];
            }
            #pragma unroll
            for (int j = 0; j < 13; ++j) {
                int r = j * 16 + (lane & 15);
                bf16x8 bj = *(const bf16x8*)&Bf[r * 64 + (kk ^ ((r & 7) << 3))];
                acc[j] = __builtin_amdgcn_mfma_f32_16x16x32_bf16(af, bj, acc[j], 0, 0, 0);
            }
        }
    }
    const int cl = lane & 15;
    {
        float t0 = -1e30f, t1 = -1e30f, t2 = -1e30f, t3 = -1e30f;
        #pragma unroll
        for (int j = 0; j < 13; ++j) {
            if (j * 16 + cl >= 196) continue;
            #pragma unroll
            for (int r = 0; r < 4; ++r) top4_insert(acc[j][r], t0, t1, t2, t3);
        }
        #pragma unroll
        for (int m = 1; m <= 8; m <<= 1) {
            float u0 = __shfl_xor(t0, m), u1 = __shfl_xor(t1, m);
            float u2 = __shfl_xor(t2, m), u3 = __shfl_xor(t3, m);
            top4_insert(u0, t0, t1, t2, t3);
            top4_insert(u1, t0, t1, t2, t3);
            top4_insert(u2, t0, t1, t2, t3);
            top4_insert(u3, t0, t1, t2, t3);
        }
        if (cl == 0) {
            int proto = pb * 16 + wid * 4 + (lane >> 4);
            if (proto < 2000) {
                float sl[4], fac = 1e-10f;
                #pragma unroll
                for (int i = 0; i < 4; ++i) {
                    sl[i] = 1.f / (1.f + expf(-psel[proto * 4 + i] * 100.f));
                    fac += sl[i];
                }
                float score = (t0 * sl[0] + t1 * sl[1] + t2 * sl[2] + t3 * sl[3]) * 4.f / fac;
                out[6144 + (size_t)b * 2000 + proto] = score;
            }
        }
    }
}

// ---------------------------------------------------------------- host launcher
extern "C" void kernel_launch(void* const* d_in, const int* in_sizes, int n_in,
                              void* d_out, int out_size, void* d_ws, size_t ws_size,
                              hipStream_t stream) {
    const float* x       = (const float*)d_in[0];
    const float* patch_w = (const float*)d_in[1];
    const float* patch_b = (const float*)d_in[2];
    const float* cls_tok = (const float*)d_in[3];
    const float* pos     = (const float*)d_in[4];
    const float* ln1_s   = (const float*)d_in[5];
    const float* ln1_b   = (const float*)d_in[6];
    const float* qkv_w   = (const float*)d_in[7];
    const float* qkv_b   = (const float*)d_in[8];
    const float* proj_w  = (const float*)d_in[9];
    const float* proj_b  = (const float*)d_in[10];
    const float* ln2_s   = (const float*)d_in[11];
    const float* ln2_b   = (const float*)d_in[12];
    const float* fc1_w   = (const float*)d_in[13];
    const float* fc1_b   = (const float*)d_in[14];
    const float* fc2_w   = (const float*)d_in[15];
    const float* fc2_b   = (const float*)d_in[16];
    const float* norm_s  = (const float*)d_in[17];
    const float* norm_b  = (const float*)d_in[18];
    const float* proto   = (const float*)d_in[19];
    const float* psel    = (const float*)d_in[20];
    float* out = (float*)d_out;
    char* w = (char*)d_ws;

    __hip_bfloat16* wPb  = (__hip_bfloat16*)(w);             // 589824
    u16*            wQ   = (u16*)(w + 589824);               // 5308416
    u16*            wPr  = (u16*)(w + 5898240);              // 1769472
    u16*            wF1  = (u16*)(w + 7667712);              // 7077888
    u16*            wF2  = (u16*)(w + 14745600);             // 7077888
    __hip_bfloat16* Acol = (__hip_bfloat16*)(w + 21823488);  // 4816896
    float*          tok  = (float*)         (w + 31457280);  // 4841472
    u16*            hbf  = (u16*)(w + 36298752);             // 2420736
    u16*            qkvb = (u16*)(w + 38719488);             // 7262208
    u16*            aob  = (u16*)(w + 53243904);             // 2420736
    u16*            hbig = (u16*)(w + 55664640);             // 9682944
    u16*            fnb  = (u16*)(w + 70189056);             // 2408448
    __hip_bfloat16* pnb  = (__hip_bfloat16*)(w + 72597504);  // 6144000

    k_prep<<<22928, 256, 0, stream>>>(patch_w, wPb, cls_tok, pos, tok,
                                      qkv_w, (__hip_bfloat16*)wQ,
                                      proj_w, (__hip_bfloat16*)wPr,
                                      fc1_w, (__hip_bfloat16*)wF1,
                                      fc2_w, (__hip_bfloat16*)wF2,
                                      x, Acol, proto, pnb);
    k_patch_tok<<<dim3(6, 25), 256, 0, stream>>>((const u16*)Acol, (const u16*)wPb, patch_b, pos, tok);

    for (int l = 0; l < 6; ++l) {
        k_ln<<<788, 256, 0, stream>>>(tok, ln1_s + l * 384, ln1_b + l * 384, hbf);
        k_mfma_gemm64<0,0,1><<<dim3(18, 25), 256, 0, stream>>>(
            hbf, wQ + (size_t)l * 1152 * 384, qkv_b + l * 1152,
            nullptr, nullptr, (__hip_bfloat16*)qkvb, MROWS, 1152, 384);
        k_attn_mfma<<<dim3(96, 2), 256, 0, stream>>>(qkvb, aob);
        k_mfma_gemm64<1,0,0><<<dim3(6, 25), 256, 0, stream>>>(
            aob, wPr + (size_t)l * 384 * 384, proj_b + l * 384,
            tok, tok, nullptr, MROWS, 384, 384);
        k_ln<<<788, 256, 0, stream>>>(tok, ln2_s + l * 384, ln2_b + l * 384, hbf);
        k_mfma_gemm64<0,1,1><<<dim3(24, 25), 256, 0, stream>>>(
            hbf, wF1 + (size_t)l * 384 * 1536, fc1_b + l * 1536,
            nullptr, nullptr, (__hip_bfloat16*)hbig, MROWS, 1536, 384);
        k_mfma_gemm64<1,0,0><<<dim3(6, 25), 256, 0, stream>>>(
            hbig, wF2 + (size_t)l * 1536 * 384, fc2_b + l * 384,
            tok, tok, nullptr, MROWS, 384, 1536);
    }

    k_fnln<<<788, 256, 0, stream>>>(tok, norm_s, norm_b, fnb, out);
    k_dist_mfma<<<2016, 256, 0, stream>>>((const __hip_bfloat16*)fnb, pnb, psel, out);
}